// Round 2
// baseline (235.104 us; speedup 1.0000x reference)
//
#include <hip/hip_runtime.h>
#include <stdint.h>

// ---------------------------------------------------------------------------
// WeightGenerator_V4: fused implementation, round 1.
// K1: 512 blocks (1 output pixel each): gate 1x1conv+BN+StarReLU, grouped 3x3,
//     dw3x3, dw5x5, multiply -> xc bf16 [pix][128]; also w_lin -> bf16.
// K2: per 8x8 patch: regenerate W(256x256) in 32-ch LDS chunks from wlin@xc
//     via MFMA, immediately consume with MFMA against Y patch. 48 KB LDS ->
//     3 blocks/CU. Y staged with float4 loads + LDS fp32 transpose (scratch
//     unioned with the W chunk buffer). wdec never touches HBM.
// ---------------------------------------------------------------------------

typedef __attribute__((ext_vector_type(8))) short short8;
typedef __attribute__((ext_vector_type(4))) float f32x4;

#define BN_EPS 1e-5f

__device__ __forceinline__ unsigned short f2bf(float f) {
  unsigned u = __float_as_uint(f);
  return (unsigned short)((u + 0x8000u) >> 16);
}
__device__ __forceinline__ unsigned pk2bf(float a, float b) {
  unsigned ua = __float_as_uint(a), ub = __float_as_uint(b);
  return ((ua + 0x8000u) >> 16) | ((ub + 0x8000u) & 0xFFFF0000u);
}
__device__ __forceinline__ float bf2f(short s) {
  return __uint_as_float(((unsigned)(unsigned short)s) << 16);
}

// =====================  K1: feature/gate branch -> xc  =====================
// 512 blocks = 2b x 16h x 16w, one output pixel per block, 256 threads.
__global__ __launch_bounds__(256) void k1_features(
    const float* __restrict__ x, const float* __restrict__ w_cr, const float* __restrict__ b_cr,
    const float* __restrict__ w_dw3, const float* __restrict__ b_dw3,
    const float* __restrict__ w_dw7, const float* __restrict__ b_dw7,
    const float* __restrict__ w_gate, const float* __restrict__ b_gate,
    const float* __restrict__ bn_gamma, const float* __restrict__ bn_beta,
    const float* __restrict__ bn_mean, const float* __restrict__ bn_var,
    const float* __restrict__ sr_scale, const float* __restrict__ sr_bias,
    const float* __restrict__ w_lin, short* __restrict__ wlin_bf, short* __restrict__ xc_bf)
{
  __shared__ __align__(16) short xs[256 * 64];  // x window (h-3..h+4, w-3..w+4) bf16
  __shared__ float xrs[64 * 28];                // xr 5x5 halo per cr (pos=ry*5+rx)
  __shared__ float xcen[256];                   // center x vector
  __shared__ float gs[128];                     // gate values

  int blk = blockIdx.x;
  int b = blk >> 8, h = (blk >> 4) & 15, w = blk & 15;
  int t = threadIdx.x;

  // w_lin fp32 -> bf16 (1 element/thread, 512*256 = full 131072)
  { int idx = blk * 256 + t; wlin_bf[idx] = (short)f2bf(w_lin[idx]); }

  // stage 8x8 x window, zero-padded
  const float* xb = x + b * 65536;
  #pragma unroll 8
  for (int i = 0; i < 64; ++i) {
    int idx = i * 256 + t;
    int c = idx >> 6, pos = idx & 63;
    int gy = h - 3 + (pos >> 3), gx = w - 3 + (pos & 7);
    float v = 0.f;
    if (gy >= 0 && gy < 16 && gx >= 0 && gx < 16) v = xb[c * 256 + gy * 16 + gx];
    xs[idx] = (short)f2bf(v);
  }
  __syncthreads();

  // grouped 3x3 conv -> xr on 5x5 halo (zero outside image)
  for (int i = 0; i < 8; ++i) {
    int idx = i * 256 + t;                 // 64cr x 32 padded slots
    int cr = idx >> 5, pos = idx & 31;
    if (pos < 25) {
      int ry = pos / 5, rx = pos - ry * 5;
      int gy = h - 2 + ry, gx = w - 2 + rx;
      float a = 0.f;
      if (gy >= 0 && gy < 16 && gx >= 0 && gx < 16) {
        a = b_cr[cr];
        #pragma unroll
        for (int ii = 0; ii < 4; ++ii) {
          const float* wp = w_cr + (cr * 4 + ii) * 9;
          const short* xp = xs + (cr * 4 + ii) * 64 + ry * 8 + rx;  // window (ry+ky, rx+kx)
          #pragma unroll
          for (int ky = 0; ky < 3; ++ky)
            #pragma unroll
            for (int kx = 0; kx < 3; ++kx)
              a += wp[ky * 3 + kx] * bf2f(xp[ky * 8 + kx]);
        }
      }
      xrs[cr * 28 + pos] = a;
    }
  }
  // center pixel = window (3,3)
  xcen[t] = bf2f(xs[t * 64 + 27]);
  __syncthreads();

  // gate: o = t>>1, each thread half the dot, shfl_xor combine
  int o = t >> 1, half = t & 1;
  {
    const float* wrow = w_gate + o * 256 + half * 128;
    const float* xcn  = xcen + half * 128;
    float ga = 0.f;
    #pragma unroll 8
    for (int ci = 0; ci < 128; ci += 4) {
      float4 wv = *(const float4*)(wrow + ci);
      float4 xv = *(const float4*)(xcn + ci);
      ga += wv.x * xv.x + wv.y * xv.y + wv.z * xv.z + wv.w * xv.w;
    }
    ga += __shfl_xor(ga, 1);
    float inv = bn_gamma[o] * rsqrtf(bn_var[o] + BN_EPS);
    float gg = (ga + b_gate[o] - bn_mean[o]) * inv + bn_beta[o];
    gg = fmaxf(gg, 0.f);
    gg = sr_scale[0] * gg * gg + sr_bias[0];
    if (half == 0) gs[o] = gg;
  }
  __syncthreads();

  // depthwise 3x3 / 5x5 on xr halo, multiply by gate, store bf16
  if (t < 128) {
    int oc = t;
    float f0;
    if (oc < 64) {
      f0 = b_dw3[oc];
      const float* wp = w_dw3 + oc * 9;
      const float* xp = xrs + oc * 28;
      #pragma unroll
      for (int ky = 0; ky < 3; ++ky)
        #pragma unroll
        for (int kx = 0; kx < 3; ++kx)
          f0 += wp[ky * 3 + kx] * xp[(ky + 1) * 5 + kx + 1];
    } else {
      int c5 = oc - 64;
      f0 = b_dw7[c5];
      const float* wp = w_dw7 + c5 * 25;
      const float* xp = xrs + c5 * 28;
      #pragma unroll
      for (int ky = 0; ky < 5; ++ky)
        #pragma unroll
        for (int kx = 0; kx < 5; ++kx)
          f0 += wp[ky * 5 + kx] * xp[ky * 5 + kx];
    }
    int pix = (b * 16 + h) * 16 + w;
    xc_bf[pix * 128 + oc] = (short)f2bf(f0 * gs[oc]);
  }
}

// =====================  K2: fused W-gen + dynamic conv  =====================
// 512 blocks (one per patch), 256 threads = 4 waves, 48 KB LDS -> 3 blocks/CU.
__global__ __launch_bounds__(256, 3) void k2_dynconv(
    const float* __restrict__ y, const float* __restrict__ b_lin,
    const short* __restrict__ wlin_bf, const short* __restrict__ xc_bf,
    float* __restrict__ out)
{
  __shared__ __align__(16) short Ylds[16384];  // Y^T [pix][256c], 16B-chunk swizzle, 32 KB
  __shared__ __align__(16) short Wlds[8192];   // W chunk [256e][32cl], swizzled, 16 KB
  float* scratch = (float*)Wlds;               // fp32 [64c][64pix] staging transpose (union)

  int blk = blockIdx.x;
  int b = blk >> 8, f = (blk >> 4) & 15, g = blk & 15;
  int tid = threadIdx.x;
  int wave = tid >> 6, lane = tid & 63;
  int quad = lane >> 4, l16 = lane & 15;

  // W-gen B-operand: xc vector of this pixel (issue early)
  short8 xfrag = {0, 0, 0, 0, 0, 0, 0, 0};
  if (quad < 2 && l16 < 8) {
    int pix = (b * 16 + f) * 16 + g;
    xfrag = *(const short8*)(xc_bf + pix * 128 + l16 * 16 + quad * 8);
  }

  const float* yb = y + b * 4194304 + (f * 8) * 128 + g * 8;

  // ---- stage Y patch: 4 chunks of 64 ch, float4 loads + LDS transpose ----
  int c_of = tid >> 4, pf_of = tid & 15;       // 64 c x 16 pixel-float4s per chunk
  float4 v[4];
  #pragma unroll
  for (int it = 0; it < 4; ++it)
    v[it] = *(const float4*)(yb + (it * 16 + c_of) * 16384 + (pf_of >> 1) * 128 + (pf_of & 1) * 4);

  for (int sc = 0; sc < 4; ++sc) {
    #pragma unroll
    for (int it = 0; it < 4; ++it)
      *(float4*)&scratch[(it * 16 + c_of) * 64 + pf_of * 4] = v[it];
    // prefetch next chunk while transpose runs
    if (sc < 3) {
      #pragma unroll
      for (int it = 0; it < 4; ++it)
        v[it] = *(const float4*)(yb + ((sc + 1) * 64 + it * 16 + c_of) * 16384 + (pf_of >> 1) * 128 + (pf_of & 1) * 4);
    }
    __syncthreads();
    #pragma unroll
    for (int tt = 0; tt < 2; ++tt) {
      int task = tt * 256 + tid;
      int pix = task & 63, cg = task >> 6;     // 64 pix x 8 c-groups
      float s0 = scratch[(cg * 8 + 0) * 64 + pix];
      float s1 = scratch[(cg * 8 + 1) * 64 + pix];
      float s2 = scratch[(cg * 8 + 2) * 64 + pix];
      float s3 = scratch[(cg * 8 + 3) * 64 + pix];
      float s4 = scratch[(cg * 8 + 4) * 64 + pix];
      float s5 = scratch[(cg * 8 + 5) * 64 + pix];
      float s6 = scratch[(cg * 8 + 6) * 64 + pix];
      float s7 = scratch[(cg * 8 + 7) * 64 + pix];
      uint4 pk;
      pk.x = pk2bf(s0, s1); pk.y = pk2bf(s2, s3);
      pk.z = pk2bf(s4, s5); pk.w = pk2bf(s6, s7);
      int chunk = sc * 8 + cg;
      int phys = chunk ^ (pix & 7);
      *(uint4*)&Ylds[pix * 256 + phys * 8] = pk;
    }
    __syncthreads();
  }

  f32x4 acc[4][4];
  f32x4 zero4 = {0.f, 0.f, 0.f, 0.f};
  #pragma unroll
  for (int et = 0; et < 4; ++et)
    #pragma unroll
    for (int nt = 0; nt < 4; ++nt)
      acc[et][nt] = zero4;

  for (int cc = 0; cc < 8; ++cc) {             // 32-channel K-chunks
    // ---- W-gen: 16 MFMA tiles per wave ----
    #pragma unroll 4
    for (int i = 0; i < 16; ++i) {
      int tt = wave * 16 + i;                  // 64 tiles/chunk
      int e31 = tt >> 1, sub = tt & 1;
      int o0 = e31 * 256 + cc * 32 + sub * 16;
      short8 af = {0, 0, 0, 0, 0, 0, 0, 0};    // A[m=l16][k=quad*8+j], k>=16 pad
      if (quad < 2) af = *(const short8*)(wlin_bf + (o0 + l16) * 16 + quad * 8);
      f32x4 d = __builtin_amdgcn_mfma_f32_16x16x32_bf16(af, xfrag, zero4, 0, 0, 0);
      if (l16 < 8) {                           // D col = group = l16
        float4 bv = *(const float4*)(b_lin + o0 + quad * 4);
        int e = l16 * 32 + e31;
        int cl = sub * 16 + quad * 4;
        int phys = ((cl >> 3) ^ ((e >> 1) & 3) ^ ((e >> 5) & 3)) & 3;
        uint2 pk; pk.x = pk2bf(d[0] + bv.x, d[1] + bv.y);
        pk.y = pk2bf(d[2] + bv.z, d[3] + bv.w);
        *(uint2*)&Wlds[e * 32 + phys * 8 + (cl & 7)] = pk;
      }
    }
    __syncthreads();
    // ---- main matmul: 16 MFMA per wave over this 32-ch chunk ----
    short8 A[4], Bf[4];
    #pragma unroll
    for (int et = 0; et < 4; ++et) {
      int e = wave * 64 + et * 16 + l16;
      int phys = (quad ^ ((e >> 1) & 3) ^ ((e >> 5) & 3)) & 3;
      A[et] = *(const short8*)&Wlds[e * 32 + phys * 8];
    }
    int chunk = cc * 4 + quad;
    #pragma unroll
    for (int nt = 0; nt < 4; ++nt) {
      int nn = nt * 16 + l16;
      int phys = chunk ^ (nn & 7);
      Bf[nt] = *(const short8*)&Ylds[nn * 256 + phys * 8];
    }
    #pragma unroll
    for (int et = 0; et < 4; ++et)
      #pragma unroll
      for (int nt = 0; nt < 4; ++nt)
        acc[et][nt] = __builtin_amdgcn_mfma_f32_16x16x32_bf16(A[et], Bf[nt], acc[et][nt], 0, 0, 0);
    __syncthreads();
  }

  // ---- epilogue: D row = e (quad*4+r), col = pixel (l16) ----
  float* ob = out + b * 4194304 + (f * 8) * 128 + g * 8;
  #pragma unroll
  for (int et = 0; et < 4; ++et) {
    int e0 = wave * 64 + et * 16 + quad * 4;
    #pragma unroll
    for (int nt = 0; nt < 4; ++nt) {
      int pix = nt * 16 + l16;
      float* oa = ob + (pix >> 3) * 128 + (pix & 7);
      #pragma unroll
      for (int r = 0; r < 4; ++r)
        oa[(e0 + r) * 16384] = acc[et][nt][r];
    }
  }
}

// ============================  launcher  ============================
extern "C" void kernel_launch(void* const* d_in, const int* in_sizes, int n_in,
                              void* d_out, int out_size, void* d_ws, size_t ws_size,
                              hipStream_t stream) {
  const float* x        = (const float*)d_in[0];
  const float* y        = (const float*)d_in[1];
  const float* w_cr     = (const float*)d_in[2];
  const float* b_cr     = (const float*)d_in[3];
  const float* w_dw3    = (const float*)d_in[4];
  const float* b_dw3    = (const float*)d_in[5];
  const float* w_dw7    = (const float*)d_in[6];
  const float* b_dw7    = (const float*)d_in[7];
  const float* w_gate   = (const float*)d_in[8];
  const float* b_gate   = (const float*)d_in[9];
  const float* bn_gamma = (const float*)d_in[10];
  const float* bn_beta  = (const float*)d_in[11];
  const float* bn_mean  = (const float*)d_in[12];
  const float* bn_var   = (const float*)d_in[13];
  const float* sr_scale = (const float*)d_in[14];
  const float* sr_bias  = (const float*)d_in[15];
  const float* w_lin    = (const float*)d_in[16];
  const float* b_lin    = (const float*)d_in[17];
  float* out = (float*)d_out;

  short* xc_bf   = (short*)d_ws;                          // 131072 B
  short* wlin_bf = (short*)((char*)d_ws + 131072);        // 262144 B

  hipLaunchKernelGGL(k1_features, dim3(512), dim3(256), 0, stream,
                     x, w_cr, b_cr, w_dw3, b_dw3, w_dw7, b_dw7, w_gate, b_gate,
                     bn_gamma, bn_beta, bn_mean, bn_var, sr_scale, sr_bias,
                     w_lin, wlin_bf, xc_bf);
  hipLaunchKernelGGL(k2_dynconv, dim3(512), dim3(256), 0, stream,
                     y, b_lin, wlin_bf, xc_bf, out);
}

// Round 3
// 192.241 us; speedup vs baseline: 1.2230x; 1.2230x over previous
//
#include <hip/hip_runtime.h>
#include <stdint.h>

// ---------------------------------------------------------------------------
// WeightGenerator_V4, round 2: de-fuse for latency hiding.
//   k1a: grouped 3x3 conv -> xr fp32 (2,64,16,16), computed ONCE (no halo
//        recompute). 128 blocks.
//   k1b: per-pixel gate(1x1+BN+StarReLU) + dw3x3/dw5x5 + multiply -> xc bf16;
//        also w_lin -> bf16. 512 blocks.
//   k2a: Wd[pix][e*256+c] = w_lin @ xc  (flat: wd[n*8192+o], n=pix*8+g).
//        Pure MFMA GEMM, no LDS, no barriers, 1024 blocks. 67 MB bf16 out.
//   k2b: out_patch(256e x 64pix) = Wd_patch @ Y_patch. Y staged in LDS (bf16,
//        swizzled); A streams from global; K-loop has NO barriers.
// ---------------------------------------------------------------------------

typedef __attribute__((ext_vector_type(8))) short short8;
typedef __attribute__((ext_vector_type(4))) float f32x4;

#define BN_EPS 1e-5f

__device__ __forceinline__ unsigned short f2bf(float f) {
  unsigned u = __float_as_uint(f);
  return (unsigned short)((u + 0x8000u) >> 16);
}
__device__ __forceinline__ unsigned pk2bf(float a, float b) {
  unsigned ua = __float_as_uint(a), ub = __float_as_uint(b);
  return ((ua + 0x8000u) >> 16) | ((ub + 0x8000u) & 0xFFFF0000u);
}

// =====================  k1a: grouped 3x3 conv -> xr  =====================
// 128 blocks = 2b x 64cr, 256 threads (one output pixel each).
__global__ __launch_bounds__(256) void k1a_groupconv(
    const float* __restrict__ x, const float* __restrict__ w_cr,
    const float* __restrict__ b_cr, float* __restrict__ xr)
{
  __shared__ float xs[4][256];
  int b = blockIdx.x >> 6, cr = blockIdx.x & 63;
  int t = threadIdx.x;
  // stage 4 input channels (coalesced float4)
  {
    int ch = t >> 6, off = (t & 63) * 4;
    float4 v = *(const float4*)(x + b * 65536 + (cr * 4 + ch) * 256 + off);
    *(float4*)&xs[ch][off] = v;
  }
  __syncthreads();
  int h = t >> 4, w = t & 15;
  float a = b_cr[cr];
  #pragma unroll
  for (int ii = 0; ii < 4; ++ii) {
    const float* wp = w_cr + (cr * 4 + ii) * 9;   // scalar (uniform) loads
    #pragma unroll
    for (int ky = 0; ky < 3; ++ky) {
      int gy = h + ky - 1;
      #pragma unroll
      for (int kx = 0; kx < 3; ++kx) {
        int gx = w + kx - 1;
        float v = (gy >= 0 && gy < 16 && gx >= 0 && gx < 16) ? xs[ii][gy * 16 + gx] : 0.f;
        a += wp[ky * 3 + kx] * v;
      }
    }
  }
  xr[(b * 64 + cr) * 256 + t] = a;
}

// =====================  k1b: gate + dw + multiply -> xc  =====================
// 512 blocks (one pixel), 256 threads.
__global__ __launch_bounds__(256) void k1b_gate_dw(
    const float* __restrict__ x, const float* __restrict__ xr,
    const float* __restrict__ w_dw3, const float* __restrict__ b_dw3,
    const float* __restrict__ w_dw7, const float* __restrict__ b_dw7,
    const float* __restrict__ w_gate, const float* __restrict__ b_gate,
    const float* __restrict__ bn_gamma, const float* __restrict__ bn_beta,
    const float* __restrict__ bn_mean, const float* __restrict__ bn_var,
    const float* __restrict__ sr_scale, const float* __restrict__ sr_bias,
    const float* __restrict__ w_lin, short* __restrict__ wlin_bf, short* __restrict__ xc_bf)
{
  __shared__ float xcen[256];
  __shared__ float gs[128];
  int blk = blockIdx.x;
  int b = blk >> 8, h = (blk >> 4) & 15, w = blk & 15;
  int t = threadIdx.x;

  // w_lin fp32 -> bf16 (512 blocks x 256 = all 131072 elements)
  { int idx = blk * 256 + t; wlin_bf[idx] = (short)f2bf(w_lin[idx]); }

  // center pixel vector (one scalar load per thread)
  xcen[t] = x[b * 65536 + t * 256 + h * 16 + w];
  __syncthreads();

  // gate: o = t>>1, each thread half of the 256-dot, shfl combine
  int o = t >> 1, half = t & 1;
  {
    const float* wrow = w_gate + o * 256 + half * 128;
    const float* xcn  = xcen + half * 128;
    float ga = 0.f;
    #pragma unroll 8
    for (int ci = 0; ci < 128; ci += 4) {
      float4 wv = *(const float4*)(wrow + ci);
      float4 xv = *(const float4*)(xcn + ci);
      ga += wv.x * xv.x + wv.y * xv.y + wv.z * xv.z + wv.w * xv.w;
    }
    ga += __shfl_xor(ga, 1);
    float inv = bn_gamma[o] * rsqrtf(bn_var[o] + BN_EPS);
    float gg = (ga + b_gate[o] - bn_mean[o]) * inv + bn_beta[o];
    gg = fmaxf(gg, 0.f);
    gg = sr_scale[0] * gg * gg + sr_bias[0];
    if (half == 0) gs[o] = gg;
  }
  __syncthreads();

  // depthwise conv from global xr (L2-resident, 256 KB), multiply, store
  if (t < 128) {
    int oc = t;
    float f0;
    if (oc < 64) {
      f0 = b_dw3[oc];
      const float* wp = w_dw3 + oc * 9;
      const float* xp = xr + (b * 64 + oc) * 256;
      #pragma unroll
      for (int ky = 0; ky < 3; ++ky) {
        int gy = h + ky - 1;
        #pragma unroll
        for (int kx = 0; kx < 3; ++kx) {
          int gx = w + kx - 1;
          float v = (gy >= 0 && gy < 16 && gx >= 0 && gx < 16) ? xp[gy * 16 + gx] : 0.f;
          f0 += wp[ky * 3 + kx] * v;
        }
      }
    } else {
      int c5 = oc - 64;
      f0 = b_dw7[c5];
      const float* wp = w_dw7 + c5 * 25;
      const float* xp = xr + (b * 64 + c5) * 256;
      #pragma unroll
      for (int ky = 0; ky < 5; ++ky) {
        int gy = h + ky - 2;
        #pragma unroll
        for (int kx = 0; kx < 5; ++kx) {
          int gx = w + kx - 2;
          float v = (gy >= 0 && gy < 16 && gx >= 0 && gx < 16) ? xp[gy * 16 + gx] : 0.f;
          f0 += wp[ky * 5 + kx] * v;
        }
      }
    }
    int pix = (b * 16 + h) * 16 + w;
    xc_bf[pix * 128 + oc] = (short)f2bf(f0 * gs[oc]);
  }
}

// =====================  k2a: Wd = w_lin @ xc (+b_lin), bf16  ================
// n = pix*8+g (4096 cols), o in [0,8192). wd flat index n*8192 + o.
// 1024 blocks = 256 n-tiles x 4 o-chunks; 4 waves x 32 MFMA tiles each.
// No LDS, no barriers: pure streaming MFMA.
__global__ __launch_bounds__(256) void k2a_wgen(
    const short* __restrict__ wlin_bf, const short* __restrict__ xc_bf,
    const float* __restrict__ b_lin, short* __restrict__ wd)
{
  int blk = blockIdx.x;
  int n0 = (blk >> 2) * 16;
  int tid = threadIdx.x;
  int wave = tid >> 6, lane = tid & 63;
  int quad = lane >> 4, l16 = lane & 15;
  int obase = (blk & 3) * 2048 + wave * 512;

  // B[k=quad*8+j][n=l16] = xc_flat[(n0+l16)*16 + k], k<16 (upper half zero)
  short8 bf = {0, 0, 0, 0, 0, 0, 0, 0};
  if (quad < 2) bf = *(const short8*)(xc_bf + (n0 + l16) * 16 + quad * 8);

  f32x4 zero4 = {0.f, 0.f, 0.f, 0.f};
  #pragma unroll 8
  for (int i = 0; i < 32; ++i) {
    int o0 = obase + i * 16;
    short8 af = {0, 0, 0, 0, 0, 0, 0, 0};   // A[m=l16][k=quad*8+j], k<16
    if (quad < 2) af = *(const short8*)(wlin_bf + (o0 + l16) * 16 + quad * 8);
    f32x4 d = __builtin_amdgcn_mfma_f32_16x16x32_bf16(af, bf, zero4, 0, 0, 0);
    // D row = quad*4+r -> o = o0+quad*4+r ; col = l16 -> n = n0+l16
    float4 bv = *(const float4*)(b_lin + o0 + quad * 4);
    uint2 pk;
    pk.x = pk2bf(d[0] + bv.x, d[1] + bv.y);
    pk.y = pk2bf(d[2] + bv.z, d[3] + bv.w);
    *(uint2*)(wd + (size_t)(n0 + l16) * 8192 + o0 + quad * 4) = pk;
  }
}

// =====================  k2b: out = Wd @ Y per patch  =====================
// 512 blocks (b,f,g), 256 threads = 4 waves. LDS: Y bf16 32 KB + 16 KB fp32
// transpose scratch = 48 KB -> 3 blocks/CU. K-loop is barrier-free: A-frags
// stream from global wd (each 64B line read exactly once).
__global__ __launch_bounds__(256, 3) void k2b_dynconv(
    const float* __restrict__ y, const short* __restrict__ wd,
    float* __restrict__ out)
{
  __shared__ __align__(16) short Ylds[16384];   // [pix][256c] swizzled bf16
  __shared__ __align__(16) float scratch[4096]; // [64c][64pix] fp32 transpose

  int blk = blockIdx.x;
  int b = blk >> 8, f = (blk >> 4) & 15, g = blk & 15;
  int tid = threadIdx.x;
  int wave = tid >> 6, lane = tid & 63;
  int quad = lane >> 4, l16 = lane & 15;

  const float* yb = y + b * 4194304 + (f * 8) * 128 + g * 8;
  const short* wdp = wd + (size_t)(((b * 16 + f) * 16 + g)) * 65536;

  // ---- stage Y patch: 4 chunks of 64 ch; float4 loads + LDS transpose ----
  int c_of = tid >> 4, pf_of = tid & 15;
  float4 v[4];
  #pragma unroll
  for (int it = 0; it < 4; ++it)
    v[it] = *(const float4*)(yb + (it * 16 + c_of) * 16384 + (pf_of >> 1) * 128 + (pf_of & 1) * 4);

  for (int sc = 0; sc < 4; ++sc) {
    #pragma unroll
    for (int it = 0; it < 4; ++it)
      *(float4*)&scratch[(it * 16 + c_of) * 64 + pf_of * 4] = v[it];
    if (sc < 3) {
      #pragma unroll
      for (int it = 0; it < 4; ++it)
        v[it] = *(const float4*)(yb + ((sc + 1) * 64 + it * 16 + c_of) * 16384 + (pf_of >> 1) * 128 + (pf_of & 1) * 4);
    }
    __syncthreads();
    #pragma unroll
    for (int tt = 0; tt < 2; ++tt) {
      int task = tt * 256 + tid;
      int pix = task & 63, cg = task >> 6;     // 64 pix x 8 c-groups of 8
      float s0 = scratch[(cg * 8 + 0) * 64 + pix];
      float s1 = scratch[(cg * 8 + 1) * 64 + pix];
      float s2 = scratch[(cg * 8 + 2) * 64 + pix];
      float s3 = scratch[(cg * 8 + 3) * 64 + pix];
      float s4 = scratch[(cg * 8 + 4) * 64 + pix];
      float s5 = scratch[(cg * 8 + 5) * 64 + pix];
      float s6 = scratch[(cg * 8 + 6) * 64 + pix];
      float s7 = scratch[(cg * 8 + 7) * 64 + pix];
      uint4 pk;
      pk.x = pk2bf(s0, s1); pk.y = pk2bf(s2, s3);
      pk.z = pk2bf(s4, s5); pk.w = pk2bf(s6, s7);
      int chunk = sc * 8 + cg;                 // 8-channel group id [0,32)
      int phys = chunk ^ (pix & 7);
      *(uint4*)&Ylds[pix * 256 + phys * 8] = pk;
    }
    __syncthreads();
  }

  // ---- barrier-free K-loop: 8 chunks of 32 channels ----
  f32x4 acc[4][4];
  f32x4 zero4 = {0.f, 0.f, 0.f, 0.f};
  #pragma unroll
  for (int et = 0; et < 4; ++et)
    #pragma unroll
    for (int nt = 0; nt < 4; ++nt)
      acc[et][nt] = zero4;

  #pragma unroll 2
  for (int cc = 0; cc < 8; ++cc) {
    short8 A[4], Bf[4];
    #pragma unroll
    for (int et = 0; et < 4; ++et) {
      int e = wave * 64 + et * 16 + l16;
      A[et] = *(const short8*)(wdp + e * 256 + cc * 32 + quad * 8);
    }
    int chunk = cc * 4 + quad;
    #pragma unroll
    for (int nt = 0; nt < 4; ++nt) {
      int nn = nt * 16 + l16;
      int phys = chunk ^ (nn & 7);
      Bf[nt] = *(const short8*)&Ylds[nn * 256 + phys * 8];
    }
    #pragma unroll
    for (int et = 0; et < 4; ++et)
      #pragma unroll
      for (int nt = 0; nt < 4; ++nt)
        acc[et][nt] = __builtin_amdgcn_mfma_f32_16x16x32_bf16(A[et], Bf[nt], acc[et][nt], 0, 0, 0);
  }

  // ---- epilogue: D row=quad*4+r -> e, col=l16 -> pix ----
  float* ob = out + b * 4194304 + (f * 8) * 128 + g * 8;
  #pragma unroll
  for (int et = 0; et < 4; ++et) {
    int e0 = wave * 64 + et * 16 + quad * 4;
    #pragma unroll
    for (int nt = 0; nt < 4; ++nt) {
      int pix = nt * 16 + l16;
      float* oa = ob + (pix >> 3) * 128 + (pix & 7);
      #pragma unroll
      for (int r = 0; r < 4; ++r)
        oa[(e0 + r) * 16384] = acc[et][nt][r];
    }
  }
}

// ============================  launcher  ============================
extern "C" void kernel_launch(void* const* d_in, const int* in_sizes, int n_in,
                              void* d_out, int out_size, void* d_ws, size_t ws_size,
                              hipStream_t stream) {
  const float* x        = (const float*)d_in[0];
  const float* y        = (const float*)d_in[1];
  const float* w_cr     = (const float*)d_in[2];
  const float* b_cr     = (const float*)d_in[3];
  const float* w_dw3    = (const float*)d_in[4];
  const float* b_dw3    = (const float*)d_in[5];
  const float* w_dw7    = (const float*)d_in[6];
  const float* b_dw7    = (const float*)d_in[7];
  const float* w_gate   = (const float*)d_in[8];
  const float* b_gate   = (const float*)d_in[9];
  const float* bn_gamma = (const float*)d_in[10];
  const float* bn_beta  = (const float*)d_in[11];
  const float* bn_mean  = (const float*)d_in[12];
  const float* bn_var   = (const float*)d_in[13];
  const float* sr_scale = (const float*)d_in[14];
  const float* sr_bias  = (const float*)d_in[15];
  const float* w_lin    = (const float*)d_in[16];
  const float* b_lin    = (const float*)d_in[17];
  float* out = (float*)d_out;

  // ws layout: xc_bf 128KB | wlin_bf 256KB | xr 128KB | Wd 64MB
  short* xc_bf   = (short*)d_ws;
  short* wlin_bf = (short*)((char*)d_ws + 131072);
  float* xr      = (float*)((char*)d_ws + 131072 + 262144);
  short* wd      = (short*)((char*)d_ws + 131072 + 262144 + 131072);

  hipLaunchKernelGGL(k1a_groupconv, dim3(128), dim3(256), 0, stream, x, w_cr, b_cr, xr);
  hipLaunchKernelGGL(k1b_gate_dw, dim3(512), dim3(256), 0, stream,
                     x, xr, w_dw3, b_dw3, w_dw7, b_dw7, w_gate, b_gate,
                     bn_gamma, bn_beta, bn_mean, bn_var, sr_scale, sr_bias,
                     w_lin, wlin_bf, xc_bf);
  hipLaunchKernelGGL(k2a_wgen, dim3(1024), dim3(256), 0, stream,
                     wlin_bf, xc_bf, b_lin, wd);
  hipLaunchKernelGGL(k2b_dynconv, dim3(512), dim3(256), 0, stream, y, wd, out);
}

// Round 4
// 162.439 us; speedup vs baseline: 1.4473x; 1.1835x over previous
//
#include <hip/hip_runtime.h>
#include <stdint.h>

// ---------------------------------------------------------------------------
// WeightGenerator_V4, round 3.
//   k1a: grouped 3x3 conv -> xr fp32. 128 blocks.
//   k1b: gate(1x1+BN+StarReLU) + dw3/dw5 + mul -> xc bf16; w_lin -> bf16.
//   k2a: Wd = xc @ w_lin^T (operands SWAPPED vs r2 so lane-cols run along o:
//        stores are 16-lane contiguous 32B runs -> L2 merges to full lines).
//   k2b: out_patch = Wd_patch @ Y_patch. 512 threads (8 waves, e-split),
//        2 blocks/CU x 8 waves = 16 waves/CU. Barrier-free K-loop, A from
//        global (each line read once), Y in swizzled LDS. XCD block swizzle.
// ---------------------------------------------------------------------------

typedef __attribute__((ext_vector_type(8))) short short8;
typedef __attribute__((ext_vector_type(4))) float f32x4;

#define BN_EPS 1e-5f

__device__ __forceinline__ unsigned short f2bf(float f) {
  unsigned u = __float_as_uint(f);
  return (unsigned short)((u + 0x8000u) >> 16);
}
__device__ __forceinline__ unsigned pk2bf(float a, float b) {
  unsigned ua = __float_as_uint(a), ub = __float_as_uint(b);
  return ((ua + 0x8000u) >> 16) | ((ub + 0x8000u) & 0xFFFF0000u);
}

// =====================  k1a: grouped 3x3 conv -> xr  =====================
__global__ __launch_bounds__(256) void k1a_groupconv(
    const float* __restrict__ x, const float* __restrict__ w_cr,
    const float* __restrict__ b_cr, float* __restrict__ xr)
{
  __shared__ float xs[4][256];
  int b = blockIdx.x >> 6, cr = blockIdx.x & 63;
  int t = threadIdx.x;
  {
    int ch = t >> 6, off = (t & 63) * 4;
    float4 v = *(const float4*)(x + b * 65536 + (cr * 4 + ch) * 256 + off);
    *(float4*)&xs[ch][off] = v;
  }
  __syncthreads();
  int h = t >> 4, w = t & 15;
  float a = b_cr[cr];
  #pragma unroll
  for (int ii = 0; ii < 4; ++ii) {
    const float* wp = w_cr + (cr * 4 + ii) * 9;
    #pragma unroll
    for (int ky = 0; ky < 3; ++ky) {
      int gy = h + ky - 1;
      #pragma unroll
      for (int kx = 0; kx < 3; ++kx) {
        int gx = w + kx - 1;
        float v = (gy >= 0 && gy < 16 && gx >= 0 && gx < 16) ? xs[ii][gy * 16 + gx] : 0.f;
        a += wp[ky * 3 + kx] * v;
      }
    }
  }
  xr[(b * 64 + cr) * 256 + t] = a;
}

// =====================  k1b: gate + dw + multiply -> xc  =====================
__global__ __launch_bounds__(256) void k1b_gate_dw(
    const float* __restrict__ x, const float* __restrict__ xr,
    const float* __restrict__ w_dw3, const float* __restrict__ b_dw3,
    const float* __restrict__ w_dw7, const float* __restrict__ b_dw7,
    const float* __restrict__ w_gate, const float* __restrict__ b_gate,
    const float* __restrict__ bn_gamma, const float* __restrict__ bn_beta,
    const float* __restrict__ bn_mean, const float* __restrict__ bn_var,
    const float* __restrict__ sr_scale, const float* __restrict__ sr_bias,
    const float* __restrict__ w_lin, short* __restrict__ wlin_bf, short* __restrict__ xc_bf)
{
  __shared__ float xcen[256];
  __shared__ float gs[128];
  int blk = blockIdx.x;
  int b = blk >> 8, h = (blk >> 4) & 15, w = blk & 15;
  int t = threadIdx.x;

  { int idx = blk * 256 + t; wlin_bf[idx] = (short)f2bf(w_lin[idx]); }

  xcen[t] = x[b * 65536 + t * 256 + h * 16 + w];
  __syncthreads();

  int o = t >> 1, half = t & 1;
  {
    const float* wrow = w_gate + o * 256 + half * 128;
    const float* xcn  = xcen + half * 128;
    float ga = 0.f;
    #pragma unroll 8
    for (int ci = 0; ci < 128; ci += 4) {
      float4 wv = *(const float4*)(wrow + ci);
      float4 xv = *(const float4*)(xcn + ci);
      ga += wv.x * xv.x + wv.y * xv.y + wv.z * xv.z + wv.w * xv.w;
    }
    ga += __shfl_xor(ga, 1);
    float inv = bn_gamma[o] * rsqrtf(bn_var[o] + BN_EPS);
    float gg = (ga + b_gate[o] - bn_mean[o]) * inv + bn_beta[o];
    gg = fmaxf(gg, 0.f);
    gg = sr_scale[0] * gg * gg + sr_bias[0];
    if (half == 0) gs[o] = gg;
  }
  __syncthreads();

  if (t < 128) {
    int oc = t;
    float f0;
    if (oc < 64) {
      f0 = b_dw3[oc];
      const float* wp = w_dw3 + oc * 9;
      const float* xp = xr + (b * 64 + oc) * 256;
      #pragma unroll
      for (int ky = 0; ky < 3; ++ky) {
        int gy = h + ky - 1;
        #pragma unroll
        for (int kx = 0; kx < 3; ++kx) {
          int gx = w + kx - 1;
          float v = (gy >= 0 && gy < 16 && gx >= 0 && gx < 16) ? xp[gy * 16 + gx] : 0.f;
          f0 += wp[ky * 3 + kx] * v;
        }
      }
    } else {
      int c5 = oc - 64;
      f0 = b_dw7[c5];
      const float* wp = w_dw7 + c5 * 25;
      const float* xp = xr + (b * 64 + c5) * 256;
      #pragma unroll
      for (int ky = 0; ky < 5; ++ky) {
        int gy = h + ky - 2;
        #pragma unroll
        for (int kx = 0; kx < 5; ++kx) {
          int gx = w + kx - 2;
          float v = (gy >= 0 && gy < 16 && gx >= 0 && gx < 16) ? xp[gy * 5 * 0 + gy * 16 + gx] : 0.f;
          f0 += wp[ky * 5 + kx] * v;
        }
      }
    }
    int pix = (b * 16 + h) * 16 + w;
    xc_bf[pix * 128 + oc] = (short)f2bf(f0 * gs[oc]);
  }
}

// =====================  k2a: Wd = xc @ w_lin^T (+b_lin), bf16  ==============
// D rows (quad*4+r) = n, cols (l16) = o  ->  stores contiguous along o.
// 1024 blocks = 256 n-tiles x 4 o-chunks; wave handles 512 o (32 MFMA).
__global__ __launch_bounds__(256) void k2a_wgen(
    const short* __restrict__ wlin_bf, const short* __restrict__ xc_bf,
    const float* __restrict__ b_lin, short* __restrict__ wd)
{
  int blk = blockIdx.x;
  int n0 = (blk >> 2) * 16;
  int tid = threadIdx.x;
  int wave = tid >> 6, lane = tid & 63;
  int quad = lane >> 4, l16 = lane & 15;
  int obase = (blk & 3) * 2048 + wave * 512;

  // A[m=l16 -> n][k=quad*8+j] = xc[(n0+l16)*16 + k], k<16 (upper half zero)
  short8 af = {0, 0, 0, 0, 0, 0, 0, 0};
  if (quad < 2) af = *(const short8*)(xc_bf + (n0 + l16) * 16 + quad * 8);

  f32x4 zero4 = {0.f, 0.f, 0.f, 0.f};
  #pragma unroll 8
  for (int i = 0; i < 32; ++i) {
    int o0 = obase + i * 16;
    // B[k=quad*8+j][n=l16 -> o] = wlin[(o0+l16)*16 + k], k<16
    short8 bf = {0, 0, 0, 0, 0, 0, 0, 0};
    if (quad < 2) bf = *(const short8*)(wlin_bf + (o0 + l16) * 16 + quad * 8);
    f32x4 d = __builtin_amdgcn_mfma_f32_16x16x32_bf16(af, bf, zero4, 0, 0, 0);
    float bl = b_lin[o0 + l16];
    // D row=quad*4+r -> n, col=l16 -> o : 16-lane contiguous 32B runs
    short* wp = wd + (size_t)(n0 + quad * 4) * 8192 + o0 + l16;
    #pragma unroll
    for (int r = 0; r < 4; ++r)
      wp[(size_t)r * 8192] = (short)f2bf(d[r] + bl);
  }
}

// =====================  k2b: out = Wd @ Y per patch  =====================
// 512 blocks (XCD-swizzled), 512 threads = 8 waves (32 e-rows each).
// LDS: Ylds 32 KB + scratch 32 KB = 64 KB -> 2 blocks/CU, 16 waves/CU.
__global__ __launch_bounds__(512, 4) void k2b_dynconv(
    const float* __restrict__ y, const short* __restrict__ wd,
    float* __restrict__ out)
{
  __shared__ __align__(16) short Ylds[16384];   // [pix][256c] bf16, swizzled
  __shared__ __align__(16) float scratch[8192]; // [128c][64pix] fp32

  int phys = blockIdx.x;
  int blk = (phys & 7) * 64 + (phys >> 3);      // XCD-contiguous patches
  int b = blk >> 8, f = (blk >> 4) & 15, g = blk & 15;
  int tid = threadIdx.x;
  int wave = tid >> 6, lane = tid & 63;
  int quad = lane >> 4, l16 = lane & 15;

  const float* yb = y + b * 4194304 + (f * 8) * 128 + g * 8;
  const short* wdp = wd + (size_t)(((b * 16 + f) * 16 + g)) * 65536;

  // ---- stage Y: 2 super-chunks of 128 channels ----
  int c32 = tid >> 4, pf = tid & 15;            // 32 c x 16 pixel-float4
  for (int sch = 0; sch < 2; ++sch) {
    float4 v[4];
    #pragma unroll
    for (int it = 0; it < 4; ++it)
      v[it] = *(const float4*)(yb + (sch * 128 + it * 32 + c32) * 16384 + (pf >> 1) * 128 + (pf & 1) * 4);
    #pragma unroll
    for (int it = 0; it < 4; ++it)
      *(float4*)&scratch[(it * 32 + c32) * 64 + pf * 4] = v[it];
    __syncthreads();
    #pragma unroll
    for (int tt = 0; tt < 2; ++tt) {
      int task = tt * 512 + tid;
      int pix = task & 63, cg = task >> 6;      // 64 pix x 16 c-groups of 8
      float s0 = scratch[(cg * 8 + 0) * 64 + pix];
      float s1 = scratch[(cg * 8 + 1) * 64 + pix];
      float s2 = scratch[(cg * 8 + 2) * 64 + pix];
      float s3 = scratch[(cg * 8 + 3) * 64 + pix];
      float s4 = scratch[(cg * 8 + 4) * 64 + pix];
      float s5 = scratch[(cg * 8 + 5) * 64 + pix];
      float s6 = scratch[(cg * 8 + 6) * 64 + pix];
      float s7 = scratch[(cg * 8 + 7) * 64 + pix];
      uint4 pk;
      pk.x = pk2bf(s0, s1); pk.y = pk2bf(s2, s3);
      pk.z = pk2bf(s4, s5); pk.w = pk2bf(s6, s7);
      int chunk = sch * 16 + cg;                // 8-ch group id [0,32)
      int physc = chunk ^ (pix & 7);
      *(uint4*)&Ylds[pix * 256 + physc * 8] = pk;
    }
    __syncthreads();
  }

  // ---- barrier-free K-loop: 8 chunks of 32 channels, 2 e-tiles/wave ----
  f32x4 acc[2][4];
  f32x4 zero4 = {0.f, 0.f, 0.f, 0.f};
  #pragma unroll
  for (int et = 0; et < 2; ++et)
    #pragma unroll
    for (int nt = 0; nt < 4; ++nt)
      acc[et][nt] = zero4;

  #pragma unroll 2
  for (int cc = 0; cc < 8; ++cc) {
    short8 A[2], Bf[4];
    #pragma unroll
    for (int et = 0; et < 2; ++et) {
      int e = wave * 32 + et * 16 + l16;
      A[et] = *(const short8*)(wdp + e * 256 + cc * 32 + quad * 8);
    }
    int chunk = cc * 4 + quad;
    #pragma unroll
    for (int nt = 0; nt < 4; ++nt) {
      int nn = nt * 16 + l16;
      int physc = chunk ^ (nn & 7);
      Bf[nt] = *(const short8*)&Ylds[nn * 256 + physc * 8];
    }
    #pragma unroll
    for (int et = 0; et < 2; ++et)
      #pragma unroll
      for (int nt = 0; nt < 4; ++nt)
        acc[et][nt] = __builtin_amdgcn_mfma_f32_16x16x32_bf16(A[et], Bf[nt], acc[et][nt], 0, 0, 0);
  }

  // ---- epilogue: D row=quad*4+r -> e, col=l16 -> pix ----
  float* ob = out + b * 4194304 + (f * 8) * 128 + g * 8;
  #pragma unroll
  for (int et = 0; et < 2; ++et) {
    int e0 = wave * 32 + et * 16 + quad * 4;
    #pragma unroll
    for (int nt = 0; nt < 4; ++nt) {
      int pix = nt * 16 + l16;
      float* oa = ob + (pix >> 3) * 128 + (pix & 7);
      #pragma unroll
      for (int r = 0; r < 4; ++r)
        oa[(e0 + r) * 16384] = acc[et][nt][r];
    }
  }
}

// ============================  launcher  ============================
extern "C" void kernel_launch(void* const* d_in, const int* in_sizes, int n_in,
                              void* d_out, int out_size, void* d_ws, size_t ws_size,
                              hipStream_t stream) {
  const float* x        = (const float*)d_in[0];
  const float* y        = (const float*)d_in[1];
  const float* w_cr     = (const float*)d_in[2];
  const float* b_cr     = (const float*)d_in[3];
  const float* w_dw3    = (const float*)d_in[4];
  const float* b_dw3    = (const float*)d_in[5];
  const float* w_dw7    = (const float*)d_in[6];
  const float* b_dw7    = (const float*)d_in[7];
  const float* w_gate   = (const float*)d_in[8];
  const float* b_gate   = (const float*)d_in[9];
  const float* bn_gamma = (const float*)d_in[10];
  const float* bn_beta  = (const float*)d_in[11];
  const float* bn_mean  = (const float*)d_in[12];
  const float* bn_var   = (const float*)d_in[13];
  const float* sr_scale = (const float*)d_in[14];
  const float* sr_bias  = (const float*)d_in[15];
  const float* w_lin    = (const float*)d_in[16];
  const float* b_lin    = (const float*)d_in[17];
  float* out = (float*)d_out;

  // ws layout: xc_bf 128KB | wlin_bf 256KB | xr 128KB | Wd 64MB
  short* xc_bf   = (short*)d_ws;
  short* wlin_bf = (short*)((char*)d_ws + 131072);
  float* xr      = (float*)((char*)d_ws + 131072 + 262144);
  short* wd      = (short*)((char*)d_ws + 131072 + 262144 + 131072);

  hipLaunchKernelGGL(k1a_groupconv, dim3(128), dim3(256), 0, stream, x, w_cr, b_cr, xr);
  hipLaunchKernelGGL(k1b_gate_dw, dim3(512), dim3(256), 0, stream,
                     x, xr, w_dw3, b_dw3, w_dw7, b_dw7, w_gate, b_gate,
                     bn_gamma, bn_beta, bn_mean, bn_var, sr_scale, sr_bias,
                     w_lin, wlin_bf, xc_bf);
  hipLaunchKernelGGL(k2a_wgen, dim3(1024), dim3(256), 0, stream,
                     wlin_bf, xc_bf, b_lin, wd);
  hipLaunchKernelGGL(k2b_dynconv, dim3(512), dim3(512), 0, stream, y, wd, out);
}